// Round 7
// baseline (1060.053 us; speedup 1.0000x reference)
//
#include <hip/hip_runtime.h>
#include <math.h>

#define BATCH 256
#define NH 512
#define NCOND 1024
#define NV 32002
#define NT 15
#define NVT_F32 501   // ceil(NV/64)  (fallback fp32 path)
#define NVT_MF  251   // ceil(NV/128) (MFMA path)
#define NBLK_PRED 502 // NVT_MF * 2 batch halves (co-resident; see k_predr)
#define WT_ELEMS ((size_t)NVT_MF*65536)   // packed Whi: 251 tiles x 128x512

// splitter section sizes in float4 units
#define SP_IH 196608    // 1536*512/4
#define SP_HH 196608
#define SP_C  131072    // 512*1024/4
#define SPLIT_W_BLOCKS 16001              // NV*NH/1024
#define SPLIT_S_BLOCKS 2048               // (SP_IH+SP_HH+SP_C)/256

// rigorous 1-pass bf16 error coefficient: 2^-8 + fp32-acc ~= 0.0040.
// C = 0.011 gives ~2.8x safety margin.
#define SCAN_C 0.011f

typedef short short8 __attribute__((ext_vector_type(8)));
typedef float float4v __attribute__((ext_vector_type(4)));

__device__ __forceinline__ void async_load16(const void* g, void* l){
  __builtin_amdgcn_global_load_lds(
      (const __attribute__((address_space(1))) void*)g,
      (__attribute__((address_space(3))) void*)l, 16, 0, 0);
}

__device__ __forceinline__ void split2(float x, unsigned short& hi, unsigned short& lo){
  unsigned u = __float_as_uint(x);
  unsigned r = u + 0x7fffu + ((u >> 16) & 1u);
  hi = (unsigned short)(r >> 16);
  float fh = __uint_as_float(r & 0xffff0000u);
  float res = x - fh;
  unsigned u2 = __float_as_uint(res);
  unsigned r2 = u2 + 0x7fffu + ((u2 >> 16) & 1u);
  lo = (unsigned short)(r2 >> 16);
}

__device__ __forceinline__ unsigned short bf16rn(float x){
  unsigned u = __float_as_uint(x);
  unsigned r = u + 0x7fffu + ((u >> 16) & 1u);
  return (unsigned short)(r >> 16);
}

// orderable packing: larger val wins; tie -> smaller idx (numpy argmax semantics)
__device__ __forceinline__ unsigned long long pack_key(float v, int idx){
  unsigned u = __float_as_uint(v);
  u = (u & 0x80000000u) ? ~u : (u | 0x80000000u);
  return ((unsigned long long)u << 32) | (unsigned)(0x7fffffff - idx);
}
__device__ __forceinline__ int key_tok(unsigned long long k){
  return 0x7fffffff - (int)(unsigned)(k & 0xffffffffu);
}
__device__ __forceinline__ float key_val(unsigned long long k){
  unsigned u = (unsigned)(k >> 32);
  u = (u & 0x80000000u) ? (u ^ 0x80000000u) : ~u;
  return __uint_as_float(u);
}

// ---------------- seed token -> preds col 0 ----------------
__global__ void k_seed(const int* __restrict__ cap, int* __restrict__ preds){
  int b = threadIdx.x;
  preds[b*NT + 0] = cap[b];
}

// ---------------- W_pred fp32 -> PACKED bf16 tiles + per-block row-norm^2 max
// Packed layout == the exact linear order k_predr's staging waves consume:
// p = tile*65536 + kchunk*8192 + tt*512 + lane*8 + e, lane = rl*8 + (pq^rl).
// Every k_predr async_load16 then reads 1KB CONTIGUOUS.
__global__ __launch_bounds__(256) void k_split_w(const float* __restrict__ Wp,
    unsigned short* __restrict__ Wt, float* __restrict__ rbmax){
  __shared__ float rs[2];
  int tid = threadIdx.x;
  size_t i = (size_t)blockIdx.x * 256 + tid;
  float4 v = *(const float4*)(Wp + i*4);
  ushort4 hs = {bf16rn(v.x), bf16rn(v.y), bf16rn(v.z), bf16rn(v.w)};
  size_t i4 = i*4;
  int row = (int)(i4 >> 9);
  int col = (int)(i4 & 511);
  int t   = row >> 7,  rin = row & 127;
  int tt  = rin >> 3,  rl  = rin & 7;
  int c   = col >> 6,  cin = col & 63;
  int pq  = cin >> 3,  e   = cin & 7;   // e in {0,4}
  int lane = rl*8 + (pq ^ rl);
  size_t p = (size_t)t*65536 + (size_t)c*8192 + (size_t)tt*512 + lane*8 + e;
  *(ushort4*)(Wt + p) = hs;
  float ss = v.x*v.x + v.y*v.y + v.z*v.z + v.w*v.w;
  #pragma unroll
  for (int off = 1; off < 64; off <<= 1) ss += __shfl_xor(ss, off);
  if (tid < 2) rs[tid] = 0.f;
  __syncthreads();
  if ((tid & 63) == 0) atomicAdd(&rs[tid >> 7], ss);
  __syncthreads();
  if (tid == 0) rbmax[blockIdx.x] = fmaxf(rs[0], rs[1]);
}

// ---------------- reduce 16001 block maxima -> wn2[0] ----------------
__global__ void k_red_wn(const float* __restrict__ rbmax, float* __restrict__ wn2){
  __shared__ float s[4];
  int tid = threadIdx.x;
  float m = 0.f;
  for (int i = tid; i < SPLIT_W_BLOCKS; i += 256) m = fmaxf(m, rbmax[i]);
  #pragma unroll
  for (int off = 1; off < 64; off <<= 1) m = fmaxf(m, __shfl_xor(m, off));
  if ((tid & 63) == 0) s[tid >> 6] = m;
  __syncthreads();
  if (tid == 0) wn2[0] = fmaxf(fmaxf(s[0], s[1]), fmaxf(s[2], s[3]));
}

// ---------------- split [wih;whh] (PACKED for k_gru_mf) + W_cond ----------------
// Packed: p = ((jtile*4 + kchunk)*24 + t)*512 + lane*8 + e,
// lane = (row96&3)*16 + (slot ^ (row96&15)), row96 = glocal*16 + jr.
__global__ __launch_bounds__(256) void k_split_small(
    const float* __restrict__ wih, const float* __restrict__ whh,
    const float* __restrict__ Wc,
    unsigned short* __restrict__ W6hiP, unsigned short* __restrict__ W6loP,
    unsigned short* __restrict__ Wchi, unsigned short* __restrict__ Wclo){
  size_t i = (size_t)blockIdx.x * 256 + threadIdx.x;
  unsigned short h0,l0,h1,l1,h2,l2,h3,l3;
  if (i < SP_IH + SP_HH){
    const float* src; size_t off; int base1536;
    if (i < SP_IH){ src = wih; off = i; base1536 = 0; }
    else { src = whh; off = i - SP_IH; base1536 = 1536; }
    float4 v = *(const float4*)(src + off*4);
    split2(v.x,h0,l0); split2(v.y,h1,l1); split2(v.z,h2,l2); split2(v.w,h3,l3);
    size_t off4 = off*4;
    int row = (int)(off4 >> 9);
    int col = (int)(off4 & 511);
    int r6 = base1536 + row;
    int glocal = r6 >> 9, jrow = r6 & 511;
    int jtile = jrow >> 4, jr = jrow & 15;
    int row96 = glocal*16 + jr;
    int c = col >> 7, cin = col & 127;
    int slot = cin >> 3, e = cin & 7;   // e in {0,4}
    int lane = (row96 & 3)*16 + (slot ^ (row96 & 15));
    size_t p = ((size_t)(jtile*4 + c)*24 + (row96 >> 2))*512 + lane*8 + e;
    ushort4 hs = {h0,h1,h2,h3};
    ushort4 ls = {l0,l1,l2,l3};
    *(ushort4*)(W6hiP + p) = hs;
    *(ushort4*)(W6loP + p) = ls;
  } else {
    size_t off = i - SP_IH - SP_HH;
    float4 v = *(const float4*)(Wc + off*4);
    split2(v.x,h0,l0); split2(v.y,h1,l1); split2(v.z,h2,l2); split2(v.w,h3,l3);
    ushort4 hs = {h0,h1,h2,h3};
    ushort4 ls = {l0,l1,l2,l3};
    *(ushort4*)(Wchi + off*4) = hs;
    *(ushort4*)(Wclo + off*4) = ls;
  }
}

// ---------------- h0 = img @ W_cond^T + b_cond  (MFMA split-bf16) ----------------
__global__ __launch_bounds__(256) void k_h0_mf(
    const float* __restrict__ img,
    const unsigned short* __restrict__ Wchi, const unsigned short* __restrict__ Wclo,
    const float* __restrict__ bc,
    float* __restrict__ h0,
    unsigned short* __restrict__ hhi, unsigned short* __restrict__ hlo){
  __shared__ __align__(16) unsigned short sA[2][16*64];
  __shared__ __align__(16) unsigned short sB[2][64*64];
  int tid = threadIdx.x, w = tid >> 6, lane = tid & 63;
  int jbase = blockIdx.x * 16, bbase = blockIdx.y * 64;
  int r16 = lane & 15, q = lane >> 4;
  float4v acc = {0.f,0.f,0.f,0.f};
  for (int k0 = 0; k0 < NCOND; k0 += 64){
    { // A: 4 passes total, wave w does pass w
      int arr = w >> 1, t = w & 1;
      int a = t*8 + (lane >> 3);
      int p = (lane & 7) ^ (lane >> 3);
      const unsigned short* gs = (arr ? Wclo : Wchi) + (size_t)(jbase + a)*NCOND + k0 + p*8;
      async_load16(gs, (char*)&sA[arr][0] + t*1024);
    }
    #pragma unroll
    for (int i = 0; i < 2; i++){ // B: img fp32 -> split -> LDS
      int u = tid + 256*i;
      int b = u >> 3, s = u & 7;
      int p = s ^ (b & 7);
      const float* gp = img + (size_t)(bbase + b)*NCOND + k0 + p*8;
      float4 f0 = *(const float4*)gp, f1 = *(const float4*)(gp + 4);
      short8 hv, lv; unsigned short hh, ll;
      split2(f0.x,hh,ll); hv[0]=(short)hh; lv[0]=(short)ll;
      split2(f0.y,hh,ll); hv[1]=(short)hh; lv[1]=(short)ll;
      split2(f0.z,hh,ll); hv[2]=(short)hh; lv[2]=(short)ll;
      split2(f0.w,hh,ll); hv[3]=(short)hh; lv[3]=(short)ll;
      split2(f1.x,hh,ll); hv[4]=(short)hh; lv[4]=(short)ll;
      split2(f1.y,hh,ll); hv[5]=(short)hh; lv[5]=(short)ll;
      split2(f1.z,hh,ll); hv[6]=(short)hh; lv[6]=(short)ll;
      split2(f1.w,hh,ll); hv[7]=(short)hh; lv[7]=(short)ll;
      *(short8*)((char*)&sB[0][0] + b*128 + s*16) = hv;
      *(short8*)((char*)&sB[1][0] + b*128 + s*16) = lv;
    }
    __syncthreads();
    int rb = w*16 + r16;
    #pragma unroll
    for (int kh = 0; kh < 2; kh++){
      int pa = kh*4 + q;
      int offA = r16*128 + ((pa ^ (r16 & 7))*16);
      int offB = rb*128 + ((pa ^ (rb & 7))*16);
      short8 ah = *(const short8*)((const char*)&sA[0][0] + offA);
      short8 al = *(const short8*)((const char*)&sA[1][0] + offA);
      short8 bh = *(const short8*)((const char*)&sB[0][0] + offB);
      short8 bl = *(const short8*)((const char*)&sB[1][0] + offB);
      acc = __builtin_amdgcn_mfma_f32_16x16x32_bf16(ah, bh, acc, 0,0,0);
      acc = __builtin_amdgcn_mfma_f32_16x16x32_bf16(ah, bl, acc, 0,0,0);
      acc = __builtin_amdgcn_mfma_f32_16x16x32_bf16(al, bh, acc, 0,0,0);
    }
    __syncthreads();
  }
  int b = bbase + w*16 + r16;
  #pragma unroll
  for (int reg = 0; reg < 4; reg++){
    int j = jbase + q*4 + reg;
    float val = acc[reg] + bc[j];
    h0[(size_t)b*NH + j] = val;
    unsigned short sh, sl; split2(val, sh, sl);
    hhi[(size_t)b*NH + j] = sh;
    hlo[(size_t)b*NH + j] = sl;
  }
}

// ---------------- fused: token-from-slot -> embed/split -> GRU (MFMA) ----------------
__global__ __launch_bounds__(256) void k_gru_mf(
    const int* __restrict__ cap,
    const unsigned long long* __restrict__ slot_prev,
    const float* __restrict__ emb,
    const unsigned short* __restrict__ W6hiP, const unsigned short* __restrict__ W6loP,
    const unsigned short* __restrict__ Hhi, const unsigned short* __restrict__ Hlo,
    const float* __restrict__ bih, const float* __restrict__ bhh,
    const float* __restrict__ hprev, float* __restrict__ hnew,
    unsigned short* __restrict__ nhhi, unsigned short* __restrict__ nhlo,
    int* __restrict__ preds, float* __restrict__ hsq,
    int use_caption, int pred_col){
  __shared__ __align__(16) unsigned short sAh[96*128];
  __shared__ __align__(16) unsigned short sAl[96*128];
  __shared__ __align__(16) unsigned short sXh[32*128];
  __shared__ __align__(16) unsigned short sXl[32*128];
  __shared__ __align__(16) unsigned short sHh[32*128];
  __shared__ __align__(16) unsigned short sHl[32*128];
  __shared__ float comb[2][768];
  __shared__ int tok[32];
  int tid = threadIdx.x, w = tid >> 6, lane = tid & 63;
  int jbase = blockIdx.x * 16, bbase = blockIdx.y * 32;
  int bsub = w & 1, grp = w >> 1;
  int b16 = lane & 15, q = lane >> 4;

  if (tid < 32){
    int t;
    if (use_caption) t = cap[bbase + tid];
    else {
      t = key_tok(slot_prev[bbase + tid]);
      if (blockIdx.x == 0) preds[(bbase + tid)*NT + pred_col] = t;
    }
    tok[tid] = t;
  }
  __syncthreads();
  int tr0 = tok[tid >> 4];
  int tr1 = tok[16 + (tid >> 4)];

  float4v acc[3];
  #pragma unroll
  for (int g = 0; g < 3; g++) acc[g] = (float4v){0.f,0.f,0.f,0.f};

  for (int k0 = 0; k0 < NH; k0 += 128){
    #pragma unroll
    for (int i = 0; i < 12; i++){ // A: 48 issues, 12/wave -- packed, contiguous
      int idx = w*12 + i;
      int arr = idx >= 24, t = arr ? (idx - 24) : idx;
      const unsigned short* gs = (arr ? W6loP : W6hiP)
          + ((size_t)(blockIdx.x*4 + (k0 >> 7))*24 + t)*512 + lane*8;
      async_load16(gs, (char*)(arr ? sAl : sAh) + t*1024);
    }
    #pragma unroll
    for (int i = 0; i < 4; i++){ // H: 16 issues, 4/wave
      int idx = w*4 + i;
      int arr = idx >= 8, t = idx & 7;
      int row = t*4 + (lane >> 4);
      int slot = (lane & 15) ^ (row & 15);
      const unsigned short* gs = (arr ? Hlo : Hhi)
          + (size_t)(bbase + row)*NH + k0 + slot*8;
      async_load16(gs, (char*)(arr ? sHl : sHh) + t*1024);
    }
    #pragma unroll
    for (int i = 0; i < 2; i++){ // X: emb fp32 gather -> split -> LDS
      int u = tid + 256*i;
      int row = u >> 4, slot = u & 15;
      int phys = slot ^ (row & 15);
      int tr = i ? tr1 : tr0;
      const float* gp = emb + (size_t)tr*NH + k0 + slot*8;
      float4 f0 = *(const float4*)gp, f1 = *(const float4*)(gp + 4);
      short8 hv, lv; unsigned short hh, ll;
      split2(f0.x,hh,ll); hv[0]=(short)hh; lv[0]=(short)ll;
      split2(f0.y,hh,ll); hv[1]=(short)hh; lv[1]=(short)ll;
      split2(f0.z,hh,ll); hv[2]=(short)hh; lv[2]=(short)ll;
      split2(f0.w,hh,ll); hv[3]=(short)hh; lv[3]=(short)ll;
      split2(f1.x,hh,ll); hv[4]=(short)hh; lv[4]=(short)ll;
      split2(f1.y,hh,ll); hv[5]=(short)hh; lv[5]=(short)ll;
      split2(f1.z,hh,ll); hv[6]=(short)hh; lv[6]=(short)ll;
      split2(f1.w,hh,ll); hv[7]=(short)hh; lv[7]=(short)ll;
      *(short8*)((char*)sXh + row*256 + phys*16) = hv;
      *(short8*)((char*)sXl + row*256 + phys*16) = lv;
    }
    __syncthreads();
    #pragma unroll
    for (int kh = 0; kh < 4; kh++){
      int phys = (kh*4 + q) ^ b16;
      int boff = (bsub*16 + b16)*256 + phys*16;
      short8 bh = grp ? *(const short8*)((const char*)sHh + boff)
                      : *(const short8*)((const char*)sXh + boff);
      short8 bl = grp ? *(const short8*)((const char*)sHl + boff)
                      : *(const short8*)((const char*)sXl + boff);
      #pragma unroll
      for (int gi = 0; gi < 3; gi++){
        int row = (grp*3 + gi)*16 + b16;
        int aoff = row*256 + phys*16;
        short8 ah = *(const short8*)((const char*)sAh + aoff);
        short8 al = *(const short8*)((const char*)sAl + aoff);
        acc[gi] = __builtin_amdgcn_mfma_f32_16x16x32_bf16(ah, bh, acc[gi], 0,0,0);
        acc[gi] = __builtin_amdgcn_mfma_f32_16x16x32_bf16(ah, bl, acc[gi], 0,0,0);
        acc[gi] = __builtin_amdgcn_mfma_f32_16x16x32_bf16(al, bh, acc[gi], 0,0,0);
      }
    }
    __syncthreads();
  }

  if (grp == 1){ // h-gate waves hand off
    #pragma unroll
    for (int gi = 0; gi < 3; gi++)
      #pragma unroll
      for (int reg = 0; reg < 4; reg++)
        comb[bsub][gi*256 + b16*16 + q*4 + reg] = acc[gi][reg];
  }
  __syncthreads();
  if (grp == 0){
    int b = bbase + bsub*16 + b16;
    float ssq = 0.f;
    #pragma unroll
    for (int reg = 0; reg < 4; reg++){
      int jl = q*4 + reg;
      int j = jbase + jl;
      float hr = comb[bsub][0*256 + b16*16 + jl];
      float hz = comb[bsub][1*256 + b16*16 + jl];
      float hn = comb[bsub][2*256 + b16*16 + jl];
      float gr = acc[0][reg] + hr + bih[j] + bhh[j];
      float gz = acc[1][reg] + hz + bih[j+NH] + bhh[j+NH];
      float in_ = acc[2][reg] + bih[j+2*NH];
      float hn_ = hn + bhh[j+2*NH];
      float r = 1.f/(1.f + expf(-gr));
      float z = 1.f/(1.f + expf(-gz));
      float n = tanhf(in_ + r*hn_);
      float hp = hprev[(size_t)b*NH + j];
      float val = (1.f - z)*n + z*hp;
      hnew[(size_t)b*NH + j] = val;
      unsigned short sh, sl; split2(val, sh, sl);
      nhhi[(size_t)b*NH + j] = sh;
      nhlo[(size_t)b*NH + j] = sl;
      ssq += val*val;
    }
    ssq += __shfl_xor(ssq, 16);
    ssq += __shfl_xor(ssq, 32);
    if (q == 0) atomicAdd(hsq + b, ssq);
  }
}

// ---------------- exact fp64 dot for one (v,b), whole wave cooperates -------
__device__ __forceinline__ void wave_exact_dot(int v, int b, int lane,
    const float* __restrict__ Wp, const float* __restrict__ h,
    const float* __restrict__ bp, unsigned long long* __restrict__ slot){
  const float* wr = Wp + (size_t)v*NH + lane*8;
  const float* hr = h  + (size_t)b*NH + lane*8;
  float4 w0 = *(const float4*)wr, w1 = *(const float4*)(wr + 4);
  float4 h0 = *(const float4*)hr, h1 = *(const float4*)(hr + 4);
  double s = (double)w0.x*h0.x + (double)w0.y*h0.y
           + (double)w0.z*h0.z + (double)w0.w*h0.w
           + (double)w1.x*h1.x + (double)w1.y*h1.y
           + (double)w1.z*h1.z + (double)w1.w*h1.w;
  #pragma unroll
  for (int off = 1; off < 64; off <<= 1) s += __shfl_xor(s, off);
  if (lane == 0) atomicMax(slot + b, pack_key((float)(s + (double)bp[v]), v));
}

// ---------------- 1-pass bf16 pred + in-kernel global rescue -----------------
// GEMM is now SOFTWARE-PIPELINED (double-buffered LDS + counted vmcnt + raw
// s_barrier, the m201-verified pattern): each wave issues exactly 8
// global_load_lds per chunk; after issuing chunk c+1, s_waitcnt vmcnt(8)
// guarantees chunk c landed while c+1's loads stay in flight ACROSS the
// barrier. Round-6 PMC: 85% stall, dur==FETCH/710GBps, the serial
// {issue -> syncthreads(vmcnt0 drain) -> MFMA} loop was the bottleneck.
// Buffer-reuse proof: iteration c issues into buf[(c+1)&1], last computed in
// iteration c-1 whose trailing s_barrier precedes this issue in every wave.
__global__ __launch_bounds__(256) void k_predr(
    const unsigned short* __restrict__ Hhi,
    const unsigned short* __restrict__ Wt,
    const float* __restrict__ bp,
    const float* __restrict__ hsq,
    const float* __restrict__ wn2,
    const float* __restrict__ h,
    const float* __restrict__ Wp,
    unsigned long long* __restrict__ mslot,
    unsigned long long* __restrict__ slot,
    unsigned* __restrict__ barctr){
  __shared__ __align__(16) unsigned short sA[2][128*64];
  __shared__ __align__(16) unsigned short sB[2][128*64];
  __shared__ float sval[256];
  __shared__ int   sidx[256];
  __shared__ float thr[128];
  int tid = threadIdx.x, w = tid >> 6, lane = tid & 63;
  int vbase = blockIdx.x*128, bbase = blockIdx.y*128;
  int mhalf = w & 1, nhalf = w >> 1;
  int isA = (w < 2) ? 1 : 0;
  int th0 = (w & 1) * 8;
  int rl = lane >> 3, sl = lane & 7, pq = sl ^ rl;
  int q = lane >> 4, b16 = lane & 15;
  float4v acc[4][4];
  #pragma unroll
  for (int mi=0;mi<4;mi++)
    #pragma unroll
    for (int ni=0;ni<4;ni++) acc[mi][ni] = (float4v){0.f,0.f,0.f,0.f};

  // issue this wave's 8 loads for chunk cc into buffer pb
  #define PRED_ISSUE(cc, pb) do {                                             \
    _Pragma("unroll")                                                         \
    for (int t_ = 0; t_ < 8; t_++){                                           \
      int tt_ = th0 + t_;                                                     \
      if (isA){                                                               \
        async_load16(Wt + (size_t)blockIdx.x*65536 + (size_t)(cc)*8192        \
                        + (size_t)tt_*512 + (size_t)lane*8,                   \
                     (char*)&sA[pb][0] + tt_*1024);                           \
      } else {                                                                \
        int grow_ = bbase + tt_*8 + rl;                                       \
        async_load16(Hhi + (size_t)grow_*NH + (cc)*64 + pq*8,                 \
                     (char*)&sB[pb][0] + tt_*1024);                           \
      }                                                                       \
    }                                                                         \
  } while(0)

  PRED_ISSUE(0, 0);
  #pragma unroll
  for (int c = 0; c < 8; c++){
    int pb = c & 1;
    if (c < 7){
      PRED_ISSUE(c + 1, pb ^ 1);
      asm volatile("s_waitcnt vmcnt(8)" ::: "memory");
    } else {
      asm volatile("s_waitcnt vmcnt(0)" ::: "memory");
    }
    __builtin_amdgcn_sched_barrier(0);
    __builtin_amdgcn_s_barrier();
    #pragma unroll
    for (int kh = 0; kh < 2; kh++){
      int pa = kh*4 + q;
      short8 a8[4], b8[4];
      #pragma unroll
      for (int mi=0;mi<4;mi++){
        int r = mhalf*64 + mi*16 + b16;
        a8[mi] = *(const short8*)((const char*)&sA[pb][0] + r*128 + ((pa ^ (r & 7))*16));
      }
      #pragma unroll
      for (int ni=0;ni<4;ni++){
        int r = nhalf*64 + ni*16 + b16;
        b8[ni] = *(const short8*)((const char*)&sB[pb][0] + r*128 + ((pa ^ (r & 7))*16));
      }
      #pragma unroll
      for (int mi=0;mi<4;mi++)
        #pragma unroll
        for (int ni=0;ni<4;ni++)
          acc[mi][ni] = __builtin_amdgcn_mfma_f32_16x16x32_bf16(a8[mi], b8[ni], acc[mi][ni], 0,0,0);
    }
    __builtin_amdgcn_s_barrier();
  }
  #undef PRED_ISSUE

  // ---- phase 1 epilogue: approx per-b argmax; cache bp in regs for phase 3 ----
  float bpr[16];
  float bestv[4] = {-INFINITY,-INFINITY,-INFINITY,-INFINITY};
  int   besti[4] = {0x7fffffff,0x7fffffff,0x7fffffff,0x7fffffff};
  #pragma unroll
  for (int mi=0;mi<4;mi++){
    #pragma unroll
    for (int reg=0;reg<4;reg++){
      int v = vbase + mhalf*64 + mi*16 + q*4 + reg;
      float bpv = (v < NV) ? bp[v] : 0.f;
      bpr[mi*4+reg] = bpv;
      if (v < NV){
        #pragma unroll
        for (int ni=0;ni<4;ni++){
          float cand = acc[mi][ni][reg] + bpv;
          if (cand > bestv[ni] || (cand == bestv[ni] && v < besti[ni])){
            bestv[ni] = cand; besti[ni] = v;
          }
        }
      }
    }
  }
  #pragma unroll
  for (int ni=0;ni<4;ni++){
    #pragma unroll
    for (int off=16; off<=32; off<<=1){
      float ov = __shfl_xor(bestv[ni], off);
      int   oi = __shfl_xor(besti[ni], off);
      if (ov > bestv[ni] || (ov == bestv[ni] && oi < besti[ni])){
        bestv[ni] = ov; besti[ni] = oi;
      }
    }
    if (lane < 16){
      sval[w*64 + ni*16 + b16] = bestv[ni];
      sidx[w*64 + ni*16 + b16] = besti[ni];
    }
  }
  __syncthreads();
  if (tid < 128){
    int nh = tid >> 6;
    int wA = nh*2, wB = nh*2 + 1;
    int slotid = tid & 63;
    float vA = sval[wA*64 + slotid], vB = sval[wB*64 + slotid];
    int   iA = sidx[wA*64 + slotid], iB = sidx[wB*64 + slotid];
    bool takeB = (vB > vA) || (vB == vA && iB < iA);
    float bv = takeB ? vB : vA;
    int   bi = takeB ? iB : iA;
    atomicMax(mslot + bbase + tid, pack_key(bv, bi));
  }
  __syncthreads();

  // ---- phase 2: counter+flag device barrier (one RMW/block, load-spin) ----
  // PERF-ONLY: timeout lowers the threshold toward this block's own max ->
  // still correct (more exact dots), never expected (2 blk/CU: 66.5KB LDS).
  if (tid == 0){
    __threadfence();
    unsigned arr = atomicAdd(barctr, 1u);
    if (arr == NBLK_PRED - 1){
      __hip_atomic_store(barctr + 16, 1u, __ATOMIC_RELEASE, __HIP_MEMORY_SCOPE_AGENT);
    } else {
      int spins = 0;
      while (!__hip_atomic_load(barctr + 16, __ATOMIC_ACQUIRE, __HIP_MEMORY_SCOPE_AGENT)
             && spins < 50000){
        __builtin_amdgcn_s_sleep(16);
        spins++;
      }
    }
  }
  __syncthreads();

  // ---- phase 3: global threshold + exact rescue ----
  if (tid < 128){
    unsigned long long mk = __hip_atomic_load(mslot + bbase + tid,
                                              __ATOMIC_RELAXED, __HIP_MEMORY_SCOPE_AGENT);
    thr[tid] = key_val(mk) - 2.f*SCAN_C*sqrtf(wn2[0])*sqrtf(hsq[bbase+tid]);
  }
  __syncthreads();
  #pragma unroll
  for (int mi=0;mi<4;mi++){
    #pragma unroll
    for (int reg=0;reg<4;reg++){
      int v = vbase + mhalf*64 + mi*16 + q*4 + reg;
      bool vok = (v < NV);
      float bpv = bpr[mi*4+reg];
      #pragma unroll
      for (int ni=0;ni<4;ni++){
        int bloc = nhalf*64 + ni*16 + b16;
        bool hit = vok && (acc[mi][ni][reg] + bpv >= thr[bloc]);
        unsigned long long m = __ballot(hit);
        while (m){
          int l = __ffsll((unsigned long long)m) - 1; m &= m - 1;
          int vv = __shfl(v, l);
          int bb = __shfl(bloc, l) + bbase;
          wave_exact_dot(vv, bb, lane, Wp, h, bp, slot);
        }
      }
    }
  }
}

// ---------------- final token from slot -> preds last col ----------------
__global__ void k_fin_slot(const unsigned long long* __restrict__ slot,
                           int* __restrict__ preds){
  int b = threadIdx.x;
  preds[b*NT + (NT-1)] = key_tok(slot[b]);
}

// ================= fp32 fallback path (ws safety) =================
__global__ __launch_bounds__(256) void k_h0_fb(const float* __restrict__ img,
                                            const float* __restrict__ Wc,
                                            const float* __restrict__ bc,
                                            float* __restrict__ h0){
  __shared__ float As[64*36];
  __shared__ float Bs[64*36];
  int tid = threadIdx.x;
  int tx = tid & 15, ty = tid >> 4;
  int jbase = blockIdx.x * 64;
  int bbase = blockIdx.y * 64;
  int lrow = tid >> 3;
  int lc4  = (tid & 7) << 2;
  float acc[4][4] = {};
  for (int k0 = 0; k0 < NCOND; k0 += 32){
    #pragma unroll
    for (int rr = 0; rr < 64; rr += 32){
      *(float4*)&As[(lrow+rr)*36 + lc4] =
          *(const float4*)(img + (size_t)(bbase+lrow+rr)*NCOND + k0 + lc4);
      *(float4*)&Bs[(lrow+rr)*36 + lc4] =
          *(const float4*)(Wc + (size_t)(jbase+lrow+rr)*NCOND + k0 + lc4);
    }
    __syncthreads();
    #pragma unroll
    for (int kk = 0; kk < 32; kk += 4){
      float4 a[4], w[4];
      #pragma unroll
      for (int i=0;i<4;i++) a[i] = *(float4*)&As[(ty+16*i)*36+kk];
      #pragma unroll
      for (int j=0;j<4;j++) w[j] = *(float4*)&Bs[(tx+16*j)*36+kk];
      #pragma unroll
      for (int i=0;i<4;i++)
        #pragma unroll
        for (int j=0;j<4;j++)
          acc[i][j] += a[i].x*w[j].x + a[i].y*w[j].y + a[i].z*w[j].z + a[i].w*w[j].w;
    }
    __syncthreads();
  }
  #pragma unroll
  for (int i=0;i<4;i++){
    int b = bbase + ty + 16*i;
    #pragma unroll
    for (int j=0;j<4;j++){
      int jj = jbase + tx + 16*j;
      h0[(size_t)b*NH + jj] = acc[i][j] + bc[jj];
    }
  }
}

__global__ __launch_bounds__(256) void k_pred_f32(const float* __restrict__ h,
                                              const float* __restrict__ Wp,
                                              const float* __restrict__ bp,
                                              float* __restrict__ pval,
                                              int* __restrict__ pidx){
  __shared__ float As[64*36];
  __shared__ float Bs[64*36];
  __shared__ float rv[64*16];
  __shared__ int   ri[64*16];
  int tid = threadIdx.x;
  int tx = tid & 15, ty = tid >> 4;
  int vt = blockIdx.x;
  int vbase = vt * 64;
  int bbase = blockIdx.y * 64;
  int lrow = tid >> 3;
  int lc4  = (tid & 7) << 2;
  float acc[4][4] = {};
  for (int k0 = 0; k0 < NH; k0 += 32){
    #pragma unroll
    for (int rr = 0; rr < 64; rr += 32){
      *(float4*)&As[(lrow+rr)*36 + lc4] =
          *(const float4*)(h + (size_t)(bbase+lrow+rr)*NH + k0 + lc4);
      int v = vbase + lrow + rr;
      float4 wv = make_float4(0.f,0.f,0.f,0.f);
      if (v < NV) wv = *(const float4*)(Wp + (size_t)v*NH + k0 + lc4);
      *(float4*)&Bs[(lrow+rr)*36 + lc4] = wv;
    }
    __syncthreads();
    #pragma unroll
    for (int kk = 0; kk < 32; kk += 4){
      float4 a[4], wv[4];
      #pragma unroll
      for (int i=0;i<4;i++) a[i] = *(float4*)&As[(ty+16*i)*36+kk];
      #pragma unroll
      for (int j=0;j<4;j++) wv[j] = *(float4*)&Bs[(tx+16*j)*36+kk];
      #pragma unroll
      for (int i=0;i<4;i++)
        #pragma unroll
        for (int j=0;j<4;j++)
          acc[i][j] += a[i].x*wv[j].x + a[i].y*wv[j].y + a[i].z*wv[j].z + a[i].w*wv[j].w;
    }
    __syncthreads();
  }
  #pragma unroll
  for (int i=0;i<4;i++){
    int bl = ty + 16*i;
    float best = -INFINITY; int bidx = 0;
    #pragma unroll
    for (int j=0;j<4;j++){
      int v = vbase + tx + 16*j;
      if (v < NV){
        float val = acc[i][j] + bp[v];
        if (val > best){ best = val; bidx = v; }
      }
    }
    rv[bl*16+tx] = best; ri[bl*16+tx] = bidx;
  }
  __syncthreads();
  if (tid < 64){
    float best = -INFINITY; int bidx = 0;
    #pragma unroll
    for (int t=0;t<16;t++){
      float v = rv[tid*16+t];
      if (v > best){ best = v; bidx = ri[tid*16+t]; }
    }
    pval[vt*BATCH + bbase + tid] = best;
    pidx[vt*BATCH + bbase + tid] = bidx;
  }
}

__global__ __launch_bounds__(256) void k_gru_fb(const int* __restrict__ cap,
    const float* __restrict__ pval, const int* __restrict__ pidx,
    const float* __restrict__ emb,
    const float* __restrict__ wih, const float* __restrict__ whh,
    const float* __restrict__ bih, const float* __restrict__ bhh,
    const float* __restrict__ hprev, float* __restrict__ hnew,
    int* __restrict__ preds, int use_caption, int pred_col, int nvt){
  __shared__ int   s_tok[32];
  __shared__ float rav[32*8];
  __shared__ int   rai[32*8];
  __shared__ float xs[32*36];
  __shared__ float hs[32*36];
  __shared__ float wis[3*16*36];
  __shared__ float whs[3*16*36];
  int tid = threadIdx.x;
  int tx = tid & 15, ty = tid >> 4;
  int jbase = blockIdx.x * 16;
  int bbase = blockIdx.y * 32;

  if (use_caption){
    if (tid < 32) s_tok[tid] = cap[bbase + tid];
  } else {
    int bl = tid >> 3, l8 = tid & 7;
    float best = -INFINITY; int bidx = 0x7fffffff;
    for (int p = l8; p < nvt; p += 8){
      float v = pval[p*BATCH + bbase + bl];
      int   i = pidx[p*BATCH + bbase + bl];
      if (v > best || (v == best && i < bidx)){ best = v; bidx = i; }
    }
    rav[bl*8 + l8] = best; rai[bl*8 + l8] = bidx;
    __syncthreads();
    if (tid < 32){
      float bb = -INFINITY; int bi = 0x7fffffff;
      #pragma unroll
      for (int t=0;t<8;t++){
        float v = rav[tid*8+t]; int i = rai[tid*8+t];
        if (v > bb || (v == bb && i < bi)){ bb = v; bi = i; }
      }
      s_tok[tid] = bi;
      if (blockIdx.x == 0) preds[(bbase+tid)*NT + pred_col] = bi;
    }
  }
  __syncthreads();

  float acc[2][6] = {};
  int lrow = tid >> 3;
  int lc4  = (tid & 7) << 2;
  for (int k0 = 0; k0 < NH; k0 += 32){
    int tokr = s_tok[lrow];
    *(float4*)&xs[lrow*36 + lc4] =
        *(const float4*)(emb + (size_t)tokr*NH + k0 + lc4);
    *(float4*)&hs[lrow*36 + lc4] =
        *(const float4*)(hprev + (size_t)(bbase+lrow)*NH + k0 + lc4);
    #pragma unroll
    for (int qy = tid; qy < 768; qy += 256){
      int g  = qy >> 7;
      int r  = (qy >> 3) & 15;
      int cc = (qy & 7) << 2;
      const float* wsrc = (g < 3) ? wih : whh;
      int gg = (g < 3) ? g : (g - 3);
      float* dst = (g < 3) ? wis : whs;
      *(float4*)&dst[gg*576 + r*36 + cc] =
          *(const float4*)(wsrc + (size_t)(gg*NH + jbase + r)*NH + k0 + cc);
    }
    __syncthreads();
    #pragma unroll
    for (int kk = 0; kk < 32; kk += 4){
      float4 x0 = *(float4*)&xs[ty*36+kk];
      float4 x1 = *(float4*)&xs[(ty+16)*36+kk];
      float4 h0v = *(float4*)&hs[ty*36+kk];
      float4 h1v = *(float4*)&hs[(ty+16)*36+kk];
      #pragma unroll
      for (int g=0; g<3; g++){
        float4 wi4 = *(float4*)&wis[g*576 + tx*36 + kk];
        float4 wh4 = *(float4*)&whs[g*576 + tx*36 + kk];
        acc[0][g]   += x0.x*wi4.x + x0.y*wi4.y + x0.z*wi4.z + x0.w*wi4.w;
        acc[1][g]   += x1.x*wi4.x + x1.y*wi4.y + x1.z*wi4.z + x1.w*wi4.w;
        acc[0][3+g] += h0v.x*wh4.x + h0v.y*wh4.y + h0v.z*wh4.z + h0v.w*wh4.w;
        acc[1][3+g] += h1v.x*wh4.x + h1v.y*wh4.y + h1v.z*wh4.z + h1v.w*wh4.w;
      }
    }
    __syncthreads();
  }
  int j = jbase + tx;
  float bi_r = bih[j], bi_z = bih[j+NH], bi_n = bih[j+2*NH];
  float bh_r = bhh[j], bh_z = bhh[j+NH], bh_n = bhh[j+2*NH];
  #pragma unroll
  for (int i=0;i<2;i++){
    int b = bbase + ty + 16*i;
    float r = 1.f/(1.f + expf(-((acc[i][0]+bi_r) + (acc[i][3]+bh_r))));
    float z = 1.f/(1.f + expf(-((acc[i][1]+bi_z) + (acc[i][4]+bh_z))));
    float n = tanhf((acc[i][2]+bi_n) + r*(acc[i][5]+bh_n));
    float hp = hprev[(size_t)b*NH + j];
    hnew[(size_t)b*NH + j] = (1.f - z)*n + z*hp;
  }
}

__global__ void k_fin(const float* __restrict__ pval, const int* __restrict__ pidx,
                      int* __restrict__ preds, int col, int nvt){
  __shared__ float rav[32*8];
  __shared__ int   rai[32*8];
  int tid = threadIdx.x;
  int bbase = blockIdx.x * 32;
  int bl = tid >> 3, l8 = tid & 7;
  float best = -INFINITY; int bidx = 0x7fffffff;
  for (int p = l8; p < nvt; p += 8){
    float v = pval[p*BATCH + bbase + bl];
    int   i = pidx[p*BATCH + bbase + bl];
    if (v > best || (v == best && i < bidx)){ best = v; bidx = i; }
  }
  rav[bl*8+l8] = best; rai[bl*8+l8] = bidx;
  __syncthreads();
  if (tid < 32){
    float bb = -INFINITY; int bi = 0x7fffffff;
    #pragma unroll
    for (int t=0;t<8;t++){
      float v = rav[tid*8+t]; int i = rai[tid*8+t];
      if (v > bb || (v == bb && i < bi)){ bb = v; bi = i; }
    }
    preds[(bbase+tid)*NT + col] = bi;
  }
}

extern "C" void kernel_launch(void* const* d_in, const int* in_sizes, int n_in,
                              void* d_out, int out_size, void* d_ws, size_t ws_size,
                              hipStream_t stream){
  const int*   cap = (const int*)d_in[0];
  const float* img = (const float*)d_in[1];
  const float* emb = (const float*)d_in[2];
  const float* Wc  = (const float*)d_in[3];
  const float* bc  = (const float*)d_in[4];
  const float* wih = (const float*)d_in[5];
  const float* whh = (const float*)d_in[6];
  const float* bih = (const float*)d_in[7];
  const float* bhh = (const float*)d_in[8];
  const float* Wp  = (const float*)d_in[9];
  const float* bp  = (const float*)d_in[10];
  int* preds = (int*)d_out;

  char* p = (char*)d_ws;
  float* h0b = (float*)p;                   p += (size_t)BATCH*NH*4;
  float* h1b = (float*)p;                   p += (size_t)BATCH*NH*4;
  float* pval = (float*)p;                  p += (size_t)NVT_F32*BATCH*4;
  int*   pidx = (int*)p;                    p += (size_t)NVT_F32*BATCH*4;
  unsigned short* Hhi0 = (unsigned short*)p; p += (size_t)BATCH*NH*2;
  unsigned short* Hlo0 = (unsigned short*)p; p += (size_t)BATCH*NH*2;
  unsigned short* Hhi1 = (unsigned short*)p; p += (size_t)BATCH*NH*2;
  unsigned short* Hlo1 = (unsigned short*)p; p += (size_t)BATCH*NH*2;
  unsigned short* Wt  = (unsigned short*)p;  p += WT_ELEMS*2;            // packed W_pred
  unsigned short* W6hiP = (unsigned short*)p; p += (size_t)3072*NH*2;    // packed [wih;whh]
  unsigned short* W6loP = (unsigned short*)p; p += (size_t)3072*NH*2;
  unsigned short* Wchi = (unsigned short*)p; p += (size_t)NH*NCOND*2;
  unsigned short* Wclo = (unsigned short*)p; p += (size_t)NH*NCOND*2;
  float* rbmax = (float*)p;                  p += (size_t)SPLIT_W_BLOCKS*4 + 60; // pad to 16B
  // zero-init region (one memset): slots | mslots | hsqb | barctr | wn2
  unsigned long long* slots = (unsigned long long*)p; p += (size_t)NT*BATCH*8;
  unsigned long long* mslots = (unsigned long long*)p; p += (size_t)NT*BATCH*8;
  float* hsqb = (float*)p;                   p += (size_t)NT*BATCH*4;
  unsigned* barctr = (unsigned*)p;           p += (size_t)NT*128; // counter+flag per step
  float* wn2 = (float*)p;                    p += 16;
  size_t zero_bytes = (size_t)NT*BATCH*8*2 + (size_t)NT*BATCH*4 + (size_t)NT*128 + 16;
  size_t need = (size_t)(p - (char*)d_ws);

  bool use_mfma = (ws_size >= need);

  k_seed<<<1, 256, 0, stream>>>(cap, preds);
  float* hb[2] = {h0b, h1b};

  if (use_mfma){
    hipMemsetAsync(slots, 0, zero_bytes, stream);
    // zero the padded tail tile of Wt (rows NV..32127) so unwritten rows are 0 not NaN
    hipMemsetAsync(Wt + (size_t)250*65536, 0, (size_t)65536*2, stream);
    k_split_small<<<dim3(SPLIT_S_BLOCKS), 256, 0, stream>>>(wih, whh, Wc,
                                                            W6hiP, W6loP, Wchi, Wclo);
    k_h0_mf<<<dim3(NH/16, BATCH/64), 256, 0, stream>>>(img, Wchi, Wclo, bc,
                                                       h0b, Hhi0, Hlo0);
    unsigned short* Hhs[2] = {Hhi0, Hhi1};
    unsigned short* Hls[2] = {Hlo0, Hlo1};
    k_gru_mf<<<dim3(NH/16, BATCH/32), 256, 0, stream>>>(cap, slots, emb,
        W6hiP, W6loP, Hhs[0], Hls[0], bih, bhh,
        hb[0], hb[1], Hhs[1], Hls[1], preds, hsqb + 1*BATCH, 1, 0);
    k_split_w<<<dim3(SPLIT_W_BLOCKS), 256, 0, stream>>>(Wp, Wt, rbmax);
    k_red_wn<<<1, 256, 0, stream>>>(rbmax, wn2);
    k_predr<<<dim3(NVT_MF, 2), 256, 0, stream>>>(Hhs[1], Wt, bp,
        hsqb + 1*BATCH, wn2, hb[1], Wp,
        mslots + 1*BATCH, slots + 1*BATCH, barctr + 1*32);
    for (int s = 2; s <= NT-1; s++){
      int pi = (s-1)&1, ci = s&1;
      k_gru_mf<<<dim3(NH/16, BATCH/32), 256, 0, stream>>>(cap, slots + (size_t)(s-1)*BATCH,
          emb, W6hiP, W6loP, Hhs[pi], Hls[pi], bih, bhh,
          hb[pi], hb[ci], Hhs[ci], Hls[ci], preds, hsqb + (size_t)s*BATCH, 0, s-1);
      k_predr<<<dim3(NVT_MF, 2), 256, 0, stream>>>(Hhs[ci], Wt, bp,
          hsqb + (size_t)s*BATCH, wn2, hb[ci], Wp,
          mslots + (size_t)s*BATCH, slots + (size_t)s*BATCH, barctr + (size_t)s*32);
    }
    k_fin_slot<<<1, 256, 0, stream>>>(slots + (size_t)(NT-1)*BATCH, preds);
  } else {
    k_h0_fb<<<dim3(NH/64, BATCH/64), 256, 0, stream>>>(img, Wc, bc, h0b);
    for (int s = 1; s <= NT-1; s++){
      const float* hprev = hb[(s-1)&1];
      float* hnew = hb[s&1];
      k_gru_fb<<<dim3(NH/16, BATCH/32), 256, 0, stream>>>(cap, pval, pidx, emb, wih, whh,
                                                       bih, bhh, hprev, hnew,
                                                       preds, (s==1)?1:0, s-1, NVT_F32);
      k_pred_f32<<<dim3(NVT_F32, BATCH/64), 256, 0, stream>>>(hnew, Wp, bp, pval, pidx);
    }
    k_fin<<<dim3(BATCH/32), 256, 0, stream>>>(pval, pidx, preds, NT-1, NVT_F32);
  }
}

// Round 8
// 1004.268 us; speedup vs baseline: 1.0555x; 1.0555x over previous
//
#include <hip/hip_runtime.h>
#include <math.h>

#define BATCH 256
#define NH 512
#define NCOND 1024
#define NV 32002
#define NT 15
#define NVT_F32 501   // ceil(NV/64)  (fallback fp32 path)
#define NVT_MF  251   // ceil(NV/128) (MFMA path)
#define NBLK_PRED 512 // padded grid (8 XCDs x 32 tiles x 2 halves); 10 idle
#define WT_ELEMS ((size_t)NVT_MF*65536)   // packed Whi: 251 tiles x 128x512

// splitter section sizes in float4 units
#define SP_IH 196608    // 1536*512/4
#define SP_HH 196608
#define SP_C  131072    // 512*1024/4
#define SPLIT_W_BLOCKS 16001              // NV*NH/1024
#define SPLIT_S_BLOCKS 2048               // (SP_IH+SP_HH+SP_C)/256

// rigorous 1-pass bf16 error coefficient: 2^-8 + fp32-acc ~= 0.0040.
// C = 0.011 gives ~2.8x safety margin.
#define SCAN_C 0.011f

typedef short short8 __attribute__((ext_vector_type(8)));
typedef float float4v __attribute__((ext_vector_type(4)));

__device__ __forceinline__ void async_load16(const void* g, void* l){
  __builtin_amdgcn_global_load_lds(
      (const __attribute__((address_space(1))) void*)g,
      (__attribute__((address_space(3))) void*)l, 16, 0, 0);
}

__device__ __forceinline__ void split2(float x, unsigned short& hi, unsigned short& lo){
  unsigned u = __float_as_uint(x);
  unsigned r = u + 0x7fffu + ((u >> 16) & 1u);
  hi = (unsigned short)(r >> 16);
  float fh = __uint_as_float(r & 0xffff0000u);
  float res = x - fh;
  unsigned u2 = __float_as_uint(res);
  unsigned r2 = u2 + 0x7fffu + ((u2 >> 16) & 1u);
  lo = (unsigned short)(r2 >> 16);
}

__device__ __forceinline__ unsigned short bf16rn(float x){
  unsigned u = __float_as_uint(x);
  unsigned r = u + 0x7fffu + ((u >> 16) & 1u);
  return (unsigned short)(r >> 16);
}

// orderable packing: larger val wins; tie -> smaller idx (numpy argmax semantics)
__device__ __forceinline__ unsigned long long pack_key(float v, int idx){
  unsigned u = __float_as_uint(v);
  u = (u & 0x80000000u) ? ~u : (u | 0x80000000u);
  return ((unsigned long long)u << 32) | (unsigned)(0x7fffffff - idx);
}
__device__ __forceinline__ int key_tok(unsigned long long k){
  return 0x7fffffff - (int)(unsigned)(k & 0xffffffffu);
}
__device__ __forceinline__ float key_val(unsigned long long k){
  unsigned u = (unsigned)(k >> 32);
  u = (u & 0x80000000u) ? (u ^ 0x80000000u) : ~u;
  return __uint_as_float(u);
}

// ---------------- seed token -> preds col 0 ----------------
__global__ void k_seed(const int* __restrict__ cap, int* __restrict__ preds){
  int b = threadIdx.x;
  preds[b*NT + 0] = cap[b];
}

// ---------------- W_pred fp32 -> PACKED bf16 tiles + per-block row-norm^2 max
// Packed layout == the exact linear order k_predr's staging waves consume:
// p = tile*65536 + kchunk*8192 + tt*512 + lane*8 + e, lane = rl*8 + (pq^rl).
// Every k_predr async_load16 then reads 1KB CONTIGUOUS.
__global__ __launch_bounds__(256) void k_split_w(const float* __restrict__ Wp,
    unsigned short* __restrict__ Wt, float* __restrict__ rbmax){
  __shared__ float rs[2];
  int tid = threadIdx.x;
  size_t i = (size_t)blockIdx.x * 256 + tid;
  float4 v = *(const float4*)(Wp + i*4);
  ushort4 hs = {bf16rn(v.x), bf16rn(v.y), bf16rn(v.z), bf16rn(v.w)};
  size_t i4 = i*4;
  int row = (int)(i4 >> 9);
  int col = (int)(i4 & 511);
  int t   = row >> 7,  rin = row & 127;
  int tt  = rin >> 3,  rl  = rin & 7;
  int c   = col >> 6,  cin = col & 63;
  int pq  = cin >> 3,  e   = cin & 7;   // e in {0,4}
  int lane = rl*8 + (pq ^ rl);
  size_t p = (size_t)t*65536 + (size_t)c*8192 + (size_t)tt*512 + lane*8 + e;
  *(ushort4*)(Wt + p) = hs;
  float ss = v.x*v.x + v.y*v.y + v.z*v.z + v.w*v.w;
  #pragma unroll
  for (int off = 1; off < 64; off <<= 1) ss += __shfl_xor(ss, off);
  if (tid < 2) rs[tid] = 0.f;
  __syncthreads();
  if ((tid & 63) == 0) atomicAdd(&rs[tid >> 7], ss);
  __syncthreads();
  if (tid == 0) rbmax[blockIdx.x] = fmaxf(rs[0], rs[1]);
}

// ---------------- reduce 16001 block maxima -> wn2[0] ----------------
__global__ void k_red_wn(const float* __restrict__ rbmax, float* __restrict__ wn2){
  __shared__ float s[4];
  int tid = threadIdx.x;
  float m = 0.f;
  for (int i = tid; i < SPLIT_W_BLOCKS; i += 256) m = fmaxf(m, rbmax[i]);
  #pragma unroll
  for (int off = 1; off < 64; off <<= 1) m = fmaxf(m, __shfl_xor(m, off));
  if ((tid & 63) == 0) s[tid >> 6] = m;
  __syncthreads();
  if (tid == 0) wn2[0] = fmaxf(fmaxf(s[0], s[1]), fmaxf(s[2], s[3]));
}

// ---------------- split [wih;whh] (PACKED for k_gru_mf) + W_cond ----------------
// Packed: p = ((jtile*4 + kchunk)*24 + t)*512 + lane*8 + e,
// lane = (row96&3)*16 + (slot ^ (row96&15)), row96 = glocal*16 + jr.
__global__ __launch_bounds__(256) void k_split_small(
    const float* __restrict__ wih, const float* __restrict__ whh,
    const float* __restrict__ Wc,
    unsigned short* __restrict__ W6hiP, unsigned short* __restrict__ W6loP,
    unsigned short* __restrict__ Wchi, unsigned short* __restrict__ Wclo){
  size_t i = (size_t)blockIdx.x * 256 + threadIdx.x;
  unsigned short h0,l0,h1,l1,h2,l2,h3,l3;
  if (i < SP_IH + SP_HH){
    const float* src; size_t off; int base1536;
    if (i < SP_IH){ src = wih; off = i; base1536 = 0; }
    else { src = whh; off = i - SP_IH; base1536 = 1536; }
    float4 v = *(const float4*)(src + off*4);
    split2(v.x,h0,l0); split2(v.y,h1,l1); split2(v.z,h2,l2); split2(v.w,h3,l3);
    size_t off4 = off*4;
    int row = (int)(off4 >> 9);
    int col = (int)(off4 & 511);
    int r6 = base1536 + row;
    int glocal = r6 >> 9, jrow = r6 & 511;
    int jtile = jrow >> 4, jr = jrow & 15;
    int row96 = glocal*16 + jr;
    int c = col >> 7, cin = col & 127;
    int slot = cin >> 3, e = cin & 7;   // e in {0,4}
    int lane = (row96 & 3)*16 + (slot ^ (row96 & 15));
    size_t p = ((size_t)(jtile*4 + c)*24 + (row96 >> 2))*512 + lane*8 + e;
    ushort4 hs = {h0,h1,h2,h3};
    ushort4 ls = {l0,l1,l2,l3};
    *(ushort4*)(W6hiP + p) = hs;
    *(ushort4*)(W6loP + p) = ls;
  } else {
    size_t off = i - SP_IH - SP_HH;
    float4 v = *(const float4*)(Wc + off*4);
    split2(v.x,h0,l0); split2(v.y,h1,l1); split2(v.z,h2,l2); split2(v.w,h3,l3);
    ushort4 hs = {h0,h1,h2,h3};
    ushort4 ls = {l0,l1,l2,l3};
    *(ushort4*)(Wchi + off*4) = hs;
    *(ushort4*)(Wclo + off*4) = ls;
  }
}

// ---------------- h0 = img @ W_cond^T + b_cond  (MFMA split-bf16) ----------------
__global__ __launch_bounds__(256) void k_h0_mf(
    const float* __restrict__ img,
    const unsigned short* __restrict__ Wchi, const unsigned short* __restrict__ Wclo,
    const float* __restrict__ bc,
    float* __restrict__ h0,
    unsigned short* __restrict__ hhi, unsigned short* __restrict__ hlo){
  __shared__ __align__(16) unsigned short sA[2][16*64];
  __shared__ __align__(16) unsigned short sB[2][64*64];
  int tid = threadIdx.x, w = tid >> 6, lane = tid & 63;
  int jbase = blockIdx.x * 16, bbase = blockIdx.y * 64;
  int r16 = lane & 15, q = lane >> 4;
  float4v acc = {0.f,0.f,0.f,0.f};
  for (int k0 = 0; k0 < NCOND; k0 += 64){
    { // A: 4 passes total, wave w does pass w
      int arr = w >> 1, t = w & 1;
      int a = t*8 + (lane >> 3);
      int p = (lane & 7) ^ (lane >> 3);
      const unsigned short* gs = (arr ? Wclo : Wchi) + (size_t)(jbase + a)*NCOND + k0 + p*8;
      async_load16(gs, (char*)&sA[arr][0] + t*1024);
    }
    #pragma unroll
    for (int i = 0; i < 2; i++){ // B: img fp32 -> split -> LDS
      int u = tid + 256*i;
      int b = u >> 3, s = u & 7;
      int p = s ^ (b & 7);
      const float* gp = img + (size_t)(bbase + b)*NCOND + k0 + p*8;
      float4 f0 = *(const float4*)gp, f1 = *(const float4*)(gp + 4);
      short8 hv, lv; unsigned short hh, ll;
      split2(f0.x,hh,ll); hv[0]=(short)hh; lv[0]=(short)ll;
      split2(f0.y,hh,ll); hv[1]=(short)hh; lv[1]=(short)ll;
      split2(f0.z,hh,ll); hv[2]=(short)hh; lv[2]=(short)ll;
      split2(f0.w,hh,ll); hv[3]=(short)hh; lv[3]=(short)ll;
      split2(f1.x,hh,ll); hv[4]=(short)hh; lv[4]=(short)ll;
      split2(f1.y,hh,ll); hv[5]=(short)hh; lv[5]=(short)ll;
      split2(f1.z,hh,ll); hv[6]=(short)hh; lv[6]=(short)ll;
      split2(f1.w,hh,ll); hv[7]=(short)hh; lv[7]=(short)ll;
      *(short8*)((char*)&sB[0][0] + b*128 + s*16) = hv;
      *(short8*)((char*)&sB[1][0] + b*128 + s*16) = lv;
    }
    __syncthreads();
    int rb = w*16 + r16;
    #pragma unroll
    for (int kh = 0; kh < 2; kh++){
      int pa = kh*4 + q;
      int offA = r16*128 + ((pa ^ (r16 & 7))*16);
      int offB = rb*128 + ((pa ^ (rb & 7))*16);
      short8 ah = *(const short8*)((const char*)&sA[0][0] + offA);
      short8 al = *(const short8*)((const char*)&sA[1][0] + offA);
      short8 bh = *(const short8*)((const char*)&sB[0][0] + offB);
      short8 bl = *(const short8*)((const char*)&sB[1][0] + offB);
      acc = __builtin_amdgcn_mfma_f32_16x16x32_bf16(ah, bh, acc, 0,0,0);
      acc = __builtin_amdgcn_mfma_f32_16x16x32_bf16(ah, bl, acc, 0,0,0);
      acc = __builtin_amdgcn_mfma_f32_16x16x32_bf16(al, bh, acc, 0,0,0);
    }
    __syncthreads();
  }
  int b = bbase + w*16 + r16;
  #pragma unroll
  for (int reg = 0; reg < 4; reg++){
    int j = jbase + q*4 + reg;
    float val = acc[reg] + bc[j];
    h0[(size_t)b*NH + j] = val;
    unsigned short sh, sl; split2(val, sh, sl);
    hhi[(size_t)b*NH + j] = sh;
    hlo[(size_t)b*NH + j] = sl;
  }
}

// ---------------- fused: token-from-slot -> embed/split -> GRU (MFMA) ----------------
__global__ __launch_bounds__(256) void k_gru_mf(
    const int* __restrict__ cap,
    const unsigned long long* __restrict__ slot_prev,
    const float* __restrict__ emb,
    const unsigned short* __restrict__ W6hiP, const unsigned short* __restrict__ W6loP,
    const unsigned short* __restrict__ Hhi, const unsigned short* __restrict__ Hlo,
    const float* __restrict__ bih, const float* __restrict__ bhh,
    const float* __restrict__ hprev, float* __restrict__ hnew,
    unsigned short* __restrict__ nhhi, unsigned short* __restrict__ nhlo,
    int* __restrict__ preds, float* __restrict__ hsq,
    int use_caption, int pred_col){
  __shared__ __align__(16) unsigned short sAh[96*128];
  __shared__ __align__(16) unsigned short sAl[96*128];
  __shared__ __align__(16) unsigned short sXh[32*128];
  __shared__ __align__(16) unsigned short sXl[32*128];
  __shared__ __align__(16) unsigned short sHh[32*128];
  __shared__ __align__(16) unsigned short sHl[32*128];
  __shared__ float comb[2][768];
  __shared__ int tok[32];
  int tid = threadIdx.x, w = tid >> 6, lane = tid & 63;
  int jbase = blockIdx.x * 16, bbase = blockIdx.y * 32;
  int bsub = w & 1, grp = w >> 1;
  int b16 = lane & 15, q = lane >> 4;

  if (tid < 32){
    int t;
    if (use_caption) t = cap[bbase + tid];
    else {
      t = key_tok(slot_prev[bbase + tid]);
      if (blockIdx.x == 0) preds[(bbase + tid)*NT + pred_col] = t;
    }
    tok[tid] = t;
  }
  __syncthreads();
  int tr0 = tok[tid >> 4];
  int tr1 = tok[16 + (tid >> 4)];

  float4v acc[3];
  #pragma unroll
  for (int g = 0; g < 3; g++) acc[g] = (float4v){0.f,0.f,0.f,0.f};

  for (int k0 = 0; k0 < NH; k0 += 128){
    #pragma unroll
    for (int i = 0; i < 12; i++){ // A: 48 issues, 12/wave -- packed, contiguous
      int idx = w*12 + i;
      int arr = idx >= 24, t = arr ? (idx - 24) : idx;
      const unsigned short* gs = (arr ? W6loP : W6hiP)
          + ((size_t)(blockIdx.x*4 + (k0 >> 7))*24 + t)*512 + lane*8;
      async_load16(gs, (char*)(arr ? sAl : sAh) + t*1024);
    }
    #pragma unroll
    for (int i = 0; i < 4; i++){ // H: 16 issues, 4/wave
      int idx = w*4 + i;
      int arr = idx >= 8, t = idx & 7;
      int row = t*4 + (lane >> 4);
      int slot = (lane & 15) ^ (row & 15);
      const unsigned short* gs = (arr ? Hlo : Hhi)
          + (size_t)(bbase + row)*NH + k0 + slot*8;
      async_load16(gs, (char*)(arr ? sHl : sHh) + t*1024);
    }
    #pragma unroll
    for (int i = 0; i < 2; i++){ // X: emb fp32 gather -> split -> LDS
      int u = tid + 256*i;
      int row = u >> 4, slot = u & 15;
      int phys = slot ^ (row & 15);
      int tr = i ? tr1 : tr0;
      const float* gp = emb + (size_t)tr*NH + k0 + slot*8;
      float4 f0 = *(const float4*)gp, f1 = *(const float4*)(gp + 4);
      short8 hv, lv; unsigned short hh, ll;
      split2(f0.x,hh,ll); hv[0]=(short)hh; lv[0]=(short)ll;
      split2(f0.y,hh,ll); hv[1]=(short)hh; lv[1]=(short)ll;
      split2(f0.z,hh,ll); hv[2]=(short)hh; lv[2]=(short)ll;
      split2(f0.w,hh,ll); hv[3]=(short)hh; lv[3]=(short)ll;
      split2(f1.x,hh,ll); hv[4]=(short)hh; lv[4]=(short)ll;
      split2(f1.y,hh,ll); hv[5]=(short)hh; lv[5]=(short)ll;
      split2(f1.z,hh,ll); hv[6]=(short)hh; lv[6]=(short)ll;
      split2(f1.w,hh,ll); hv[7]=(short)hh; lv[7]=(short)ll;
      *(short8*)((char*)sXh + row*256 + phys*16) = hv;
      *(short8*)((char*)sXl + row*256 + phys*16) = lv;
    }
    __syncthreads();
    #pragma unroll
    for (int kh = 0; kh < 4; kh++){
      int phys = (kh*4 + q) ^ b16;
      int boff = (bsub*16 + b16)*256 + phys*16;
      short8 bh = grp ? *(const short8*)((const char*)sHh + boff)
                      : *(const short8*)((const char*)sXh + boff);
      short8 bl = grp ? *(const short8*)((const char*)sHl + boff)
                      : *(const short8*)((const char*)sXl + boff);
      #pragma unroll
      for (int gi = 0; gi < 3; gi++){
        int row = (grp*3 + gi)*16 + b16;
        int aoff = row*256 + phys*16;
        short8 ah = *(const short8*)((const char*)sAh + aoff);
        short8 al = *(const short8*)((const char*)sAl + aoff);
        acc[gi] = __builtin_amdgcn_mfma_f32_16x16x32_bf16(ah, bh, acc[gi], 0,0,0);
        acc[gi] = __builtin_amdgcn_mfma_f32_16x16x32_bf16(ah, bl, acc[gi], 0,0,0);
        acc[gi] = __builtin_amdgcn_mfma_f32_16x16x32_bf16(al, bh, acc[gi], 0,0,0);
      }
    }
    __syncthreads();
  }

  if (grp == 1){ // h-gate waves hand off
    #pragma unroll
    for (int gi = 0; gi < 3; gi++)
      #pragma unroll
      for (int reg = 0; reg < 4; reg++)
        comb[bsub][gi*256 + b16*16 + q*4 + reg] = acc[gi][reg];
  }
  __syncthreads();
  if (grp == 0){
    int b = bbase + bsub*16 + b16;
    float ssq = 0.f;
    #pragma unroll
    for (int reg = 0; reg < 4; reg++){
      int jl = q*4 + reg;
      int j = jbase + jl;
      float hr = comb[bsub][0*256 + b16*16 + jl];
      float hz = comb[bsub][1*256 + b16*16 + jl];
      float hn = comb[bsub][2*256 + b16*16 + jl];
      float gr = acc[0][reg] + hr + bih[j] + bhh[j];
      float gz = acc[1][reg] + hz + bih[j+NH] + bhh[j+NH];
      float in_ = acc[2][reg] + bih[j+2*NH];
      float hn_ = hn + bhh[j+2*NH];
      float r = 1.f/(1.f + expf(-gr));
      float z = 1.f/(1.f + expf(-gz));
      float n = tanhf(in_ + r*hn_);
      float hp = hprev[(size_t)b*NH + j];
      float val = (1.f - z)*n + z*hp;
      hnew[(size_t)b*NH + j] = val;
      unsigned short sh, sl; split2(val, sh, sl);
      nhhi[(size_t)b*NH + j] = sh;
      nhlo[(size_t)b*NH + j] = sl;
      ssq += val*val;
    }
    ssq += __shfl_xor(ssq, 16);
    ssq += __shfl_xor(ssq, 32);
    if (q == 0) atomicAdd(hsq + b, ssq);
  }
}

// ---------------- exact fp64 dot for one (v,b), whole wave cooperates -------
__device__ __forceinline__ void wave_exact_dot(int v, int b, int lane,
    const float* __restrict__ Wp, const float* __restrict__ h,
    const float* __restrict__ bp, unsigned long long* __restrict__ slot){
  const float* wr = Wp + (size_t)v*NH + lane*8;
  const float* hr = h  + (size_t)b*NH + lane*8;
  float4 w0 = *(const float4*)wr, w1 = *(const float4*)(wr + 4);
  float4 h0 = *(const float4*)hr, h1 = *(const float4*)(hr + 4);
  double s = (double)w0.x*h0.x + (double)w0.y*h0.y
           + (double)w0.z*h0.z + (double)w0.w*h0.w
           + (double)w1.x*h1.x + (double)w1.y*h1.y
           + (double)w1.z*h1.z + (double)w1.w*h1.w;
  #pragma unroll
  for (int off = 1; off < 64; off <<= 1) s += __shfl_xor(s, off);
  if (lane == 0) atomicMax(slot + b, pack_key((float)(s + (double)bp[v]), v));
}

// ---------------- 1-pass bf16 pred + in-kernel global rescue -----------------
// XCD-AFFINE PERSISTENT TILE MAPPING (round-8 change): grid padded to 512;
// xcd = wgid&7, m = (wgid>>3)>>1, half = (wgid>>3)&1, tile = xcd*32+m.
// Rationale: R6/R7 showed dur == FETCH/~740GB/s regardless of pipelining ->
// far-path throughput bound. Default (251,2) mapping puts tile B on XCD B%8
// (half 0) and (B+3)%8 (half 1), and re-randomizes nothing across dispatches
// -> zero L2 retention of the 33MB W stream. Affine mapping gives each XCD a
// stationary 4.2MB tile slab (L2-scale) and co-locates both halves of a tile.
// Perf-only: wrong XCD heuristic = null, never incorrect.
__global__ __launch_bounds__(256) void k_predr(
    const unsigned short* __restrict__ Hhi,
    const unsigned short* __restrict__ Wt,
    const float* __restrict__ bp,
    const float* __restrict__ hsq,
    const float* __restrict__ wn2,
    const float* __restrict__ h,
    const float* __restrict__ Wp,
    unsigned long long* __restrict__ mslot,
    unsigned long long* __restrict__ slot,
    unsigned* __restrict__ barctr){
  __shared__ __align__(16) unsigned short sA[2][128*64];
  __shared__ __align__(16) unsigned short sB[2][128*64];
  __shared__ float sval[256];
  __shared__ int   sidx[256];
  __shared__ float thr[128];
  int tid = threadIdx.x, w = tid >> 6, lane = tid & 63;
  int wg = blockIdx.x;
  int vt = (wg & 7)*32 + ((wg >> 3) >> 1);
  int half = (wg >> 3) & 1;
  if (vt >= NVT_MF){
    // idle pad block: arrive at barrier so the count completes, then exit
    if (tid == 0){
      __threadfence();
      unsigned arr = atomicAdd(barctr, 1u);
      if (arr == NBLK_PRED - 1)
        __hip_atomic_store(barctr + 16, 1u, __ATOMIC_RELEASE, __HIP_MEMORY_SCOPE_AGENT);
    }
    return;
  }
  int vbase = vt*128, bbase = half*128;
  int mhalf = w & 1, nhalf = w >> 1;
  int isA = (w < 2) ? 1 : 0;
  int th0 = (w & 1) * 8;
  int rl = lane >> 3, sl = lane & 7, pq = sl ^ rl;
  int q = lane >> 4, b16 = lane & 15;
  float4v acc[4][4];
  #pragma unroll
  for (int mi=0;mi<4;mi++)
    #pragma unroll
    for (int ni=0;ni<4;ni++) acc[mi][ni] = (float4v){0.f,0.f,0.f,0.f};

  // issue this wave's 8 loads for chunk cc into buffer pb
  #define PRED_ISSUE(cc, pb) do {                                             \
    _Pragma("unroll")                                                         \
    for (int t_ = 0; t_ < 8; t_++){                                           \
      int tt_ = th0 + t_;                                                     \
      if (isA){                                                               \
        async_load16(Wt + (size_t)vt*65536 + (size_t)(cc)*8192                \
                        + (size_t)tt_*512 + (size_t)lane*8,                   \
                     (char*)&sA[pb][0] + tt_*1024);                           \
      } else {                                                                \
        int grow_ = bbase + tt_*8 + rl;                                       \
        async_load16(Hhi + (size_t)grow_*NH + (cc)*64 + pq*8,                 \
                     (char*)&sB[pb][0] + tt_*1024);                           \
      }                                                                       \
    }                                                                         \
  } while(0)

  PRED_ISSUE(0, 0);
  #pragma unroll
  for (int c = 0; c < 8; c++){
    int pb = c & 1;
    if (c < 7){
      PRED_ISSUE(c + 1, pb ^ 1);
      asm volatile("s_waitcnt vmcnt(8)" ::: "memory");
    } else {
      asm volatile("s_waitcnt vmcnt(0)" ::: "memory");
    }
    __builtin_amdgcn_sched_barrier(0);
    __builtin_amdgcn_s_barrier();
    #pragma unroll
    for (int kh = 0; kh < 2; kh++){
      int pa = kh*4 + q;
      short8 a8[4], b8[4];
      #pragma unroll
      for (int mi=0;mi<4;mi++){
        int r = mhalf*64 + mi*16 + b16;
        a8[mi] = *(const short8*)((const char*)&sA[pb][0] + r*128 + ((pa ^ (r & 7))*16));
      }
      #pragma unroll
      for (int ni=0;ni<4;ni++){
        int r = nhalf*64 + ni*16 + b16;
        b8[ni] = *(const short8*)((const char*)&sB[pb][0] + r*128 + ((pa ^ (r & 7))*16));
      }
      #pragma unroll
      for (int mi=0;mi<4;mi++)
        #pragma unroll
        for (int ni=0;ni<4;ni++)
          acc[mi][ni] = __builtin_amdgcn_mfma_f32_16x16x32_bf16(a8[mi], b8[ni], acc[mi][ni], 0,0,0);
    }
    __builtin_amdgcn_s_barrier();
  }
  #undef PRED_ISSUE

  // ---- phase 1 epilogue: approx per-b argmax; cache bp in regs for phase 3 ----
  float bpr[16];
  float bestv[4] = {-INFINITY,-INFINITY,-INFINITY,-INFINITY};
  int   besti[4] = {0x7fffffff,0x7fffffff,0x7fffffff,0x7fffffff};
  #pragma unroll
  for (int mi=0;mi<4;mi++){
    #pragma unroll
    for (int reg=0;reg<4;reg++){
      int v = vbase + mhalf*64 + mi*16 + q*4 + reg;
      float bpv = (v < NV) ? bp[v] : 0.f;
      bpr[mi*4+reg] = bpv;
      if (v < NV){
        #pragma unroll
        for (int ni=0;ni<4;ni++){
          float cand = acc[mi][ni][reg] + bpv;
          if (cand > bestv[ni] || (cand == bestv[ni] && v < besti[ni])){
            bestv[ni] = cand; besti[ni] = v;
          }
        }
      }
    }
  }
  #pragma unroll
  for (int ni=0;ni<4;ni++){
    #pragma unroll
    for (int off=16; off<=32; off<<=1){
      float ov = __shfl_xor(bestv[ni], off);
      int   oi = __shfl_xor(besti[ni], off);
      if (ov > bestv[ni] || (ov == bestv[ni] && oi < besti[ni])){
        bestv[ni] = ov; besti[ni] = oi;
      }
    }
    if (lane < 16){
      sval[w*64 + ni*16 + b16] = bestv[ni];
      sidx[w*64 + ni*16 + b16] = besti[ni];
    }
  }
  __syncthreads();
  if (tid < 128){
    int nh = tid >> 6;
    int wA = nh*2, wB = nh*2 + 1;
    int slotid = tid & 63;
    float vA = sval[wA*64 + slotid], vB = sval[wB*64 + slotid];
    int   iA = sidx[wA*64 + slotid], iB = sidx[wB*64 + slotid];
    bool takeB = (vB > vA) || (vB == vA && iB < iA);
    float bv = takeB ? vB : vA;
    int   bi = takeB ? iB : iA;
    atomicMax(mslot + bbase + tid, pack_key(bv, bi));
  }
  __syncthreads();

  // ---- phase 2: counter+flag device barrier (one RMW/block, load-spin) ----
  // PERF-ONLY: timeout lowers the threshold toward this block's own max ->
  // still correct (more exact dots), never expected (2 blk/CU: 66.5KB LDS,
  // 512 residency slots = NBLK_PRED).
  if (tid == 0){
    __threadfence();
    unsigned arr = atomicAdd(barctr, 1u);
    if (arr == NBLK_PRED - 1){
      __hip_atomic_store(barctr + 16, 1u, __ATOMIC_RELEASE, __HIP_MEMORY_SCOPE_AGENT);
    } else {
      int spins = 0;
      while (!__hip_atomic_load(barctr + 16, __ATOMIC_ACQUIRE, __HIP_MEMORY_SCOPE_AGENT)
             && spins < 50000){
        __builtin_amdgcn_s_sleep(16);
        spins++;
      }
    }
  }
  __syncthreads();

  // ---- phase 3: global threshold + exact rescue ----
  if (tid < 128){
    unsigned long long mk = __hip_atomic_load(mslot + bbase + tid,
                                              __ATOMIC_RELAXED, __HIP_MEMORY_SCOPE_AGENT);
    thr[tid] = key_val(mk) - 2.f*SCAN_C*sqrtf(wn2[0])*sqrtf(hsq[bbase+tid]);
  }
  __syncthreads();
  #pragma unroll
  for (int mi=0;mi<4;mi++){
    #pragma unroll
    for (int reg=0;reg<4;reg++){
      int v = vbase + mhalf*64 + mi*16 + q*4 + reg;
      bool vok = (v < NV);
      float bpv = bpr[mi*4+reg];
      #pragma unroll
      for (int ni=0;ni<4;ni++){
        int bloc = nhalf*64 + ni*16 + b16;
        bool hit = vok && (acc[mi][ni][reg] + bpv >= thr[bloc]);
        unsigned long long m = __ballot(hit);
        while (m){
          int l = __ffsll((unsigned long long)m) - 1; m &= m - 1;
          int vv = __shfl(v, l);
          int bb = __shfl(bloc, l) + bbase;
          wave_exact_dot(vv, bb, lane, Wp, h, bp, slot);
        }
      }
    }
  }
}

// ---------------- final token from slot -> preds last col ----------------
__global__ void k_fin_slot(const unsigned long long* __restrict__ slot,
                           int* __restrict__ preds){
  int b = threadIdx.x;
  preds[b*NT + (NT-1)] = key_tok(slot[b]);
}

// ================= fp32 fallback path (ws safety) =================
__global__ __launch_bounds__(256) void k_h0_fb(const float* __restrict__ img,
                                            const float* __restrict__ Wc,
                                            const float* __restrict__ bc,
                                            float* __restrict__ h0){
  __shared__ float As[64*36];
  __shared__ float Bs[64*36];
  int tid = threadIdx.x;
  int tx = tid & 15, ty = tid >> 4;
  int jbase = blockIdx.x * 64;
  int bbase = blockIdx.y * 64;
  int lrow = tid >> 3;
  int lc4  = (tid & 7) << 2;
  float acc[4][4] = {};
  for (int k0 = 0; k0 < NCOND; k0 += 32){
    #pragma unroll
    for (int rr = 0; rr < 64; rr += 32){
      *(float4*)&As[(lrow+rr)*36 + lc4] =
          *(const float4*)(img + (size_t)(bbase+lrow+rr)*NCOND + k0 + lc4);
      *(float4*)&Bs[(lrow+rr)*36 + lc4] =
          *(const float4*)(Wc + (size_t)(jbase+lrow+rr)*NCOND + k0 + lc4);
    }
    __syncthreads();
    #pragma unroll
    for (int kk = 0; kk < 32; kk += 4){
      float4 a[4], w[4];
      #pragma unroll
      for (int i=0;i<4;i++) a[i] = *(float4*)&As[(ty+16*i)*36+kk];
      #pragma unroll
      for (int j=0;j<4;j++) w[j] = *(float4*)&Bs[(tx+16*j)*36+kk];
      #pragma unroll
      for (int i=0;i<4;i++)
        #pragma unroll
        for (int j=0;j<4;j++)
          acc[i][j] += a[i].x*w[j].x + a[i].y*w[j].y + a[i].z*w[j].z + a[i].w*w[j].w;
    }
    __syncthreads();
  }
  #pragma unroll
  for (int i=0;i<4;i++){
    int b = bbase + ty + 16*i;
    #pragma unroll
    for (int j=0;j<4;j++){
      int jj = jbase + tx + 16*j;
      h0[(size_t)b*NH + jj] = acc[i][j] + bc[jj];
    }
  }
}

__global__ __launch_bounds__(256) void k_pred_f32(const float* __restrict__ h,
                                              const float* __restrict__ Wp,
                                              const float* __restrict__ bp,
                                              float* __restrict__ pval,
                                              int* __restrict__ pidx){
  __shared__ float As[64*36];
  __shared__ float Bs[64*36];
  __shared__ float rv[64*16];
  __shared__ int   ri[64*16];
  int tid = threadIdx.x;
  int tx = tid & 15, ty = tid >> 4;
  int vt = blockIdx.x;
  int vbase = vt * 64;
  int bbase = blockIdx.y * 64;
  int lrow = tid >> 3;
  int lc4  = (tid & 7) << 2;
  float acc[4][4] = {};
  for (int k0 = 0; k0 < NH; k0 += 32){
    #pragma unroll
    for (int rr = 0; rr < 64; rr += 32){
      *(float4*)&As[(lrow+rr)*36 + lc4] =
          *(const float4*)(h + (size_t)(bbase+lrow+rr)*NH + k0 + lc4);
      int v = vbase + lrow + rr;
      float4 wv = make_float4(0.f,0.f,0.f,0.f);
      if (v < NV) wv = *(const float4*)(Wp + (size_t)v*NH + k0 + lc4);
      *(float4*)&Bs[(lrow+rr)*36 + lc4] = wv;
    }
    __syncthreads();
    #pragma unroll
    for (int kk = 0; kk < 32; kk += 4){
      float4 a[4], wv[4];
      #pragma unroll
      for (int i=0;i<4;i++) a[i] = *(float4*)&As[(ty+16*i)*36+kk];
      #pragma unroll
      for (int j=0;j<4;j++) wv[j] = *(float4*)&Bs[(tx+16*j)*36+kk];
      #pragma unroll
      for (int i=0;i<4;i++)
        #pragma unroll
        for (int j=0;j<4;j++)
          acc[i][j] += a[i].x*wv[j].x + a[i].y*wv[j].y + a[i].z*wv[j].z + a[i].w*wv[j].w;
    }
    __syncthreads();
  }
  #pragma unroll
  for (int i=0;i<4;i++){
    int bl = ty + 16*i;
    float best = -INFINITY; int bidx = 0;
    #pragma unroll
    for (int j=0;j<4;j++){
      int v = vbase + tx + 16*j;
      if (v < NV){
        float val = acc[i][j] + bp[v];
        if (val > best){ best = val; bidx = v; }
      }
    }
    rv[bl*16+tx] = best; ri[bl*16+tx] = bidx;
  }
  __syncthreads();
  if (tid < 64){
    float best = -INFINITY; int bidx = 0;
    #pragma unroll
    for (int t=0;t<16;t++){
      float v = rv[tid*16+t];
      if (v > best){ best = v; bidx = ri[tid*16+t]; }
    }
    pval[vt*BATCH + bbase + tid] = best;
    pidx[vt*BATCH + bbase + tid] = bidx;
  }
}

__global__ __launch_bounds__(256) void k_gru_fb(const int* __restrict__ cap,
    const float* __restrict__ pval, const int* __restrict__ pidx,
    const float* __restrict__ emb,
    const float* __restrict__ wih, const float* __restrict__ whh,
    const float* __restrict__ bih, const float* __restrict__ bhh,
    const float* __restrict__ hprev, float* __restrict__ hnew,
    int* __restrict__ preds, int use_caption, int pred_col, int nvt){
  __shared__ int   s_tok[32];
  __shared__ float rav[32*8];
  __shared__ int   rai[32*8];
  __shared__ float xs[32*36];
  __shared__ float hs[32*36];
  __shared__ float wis[3*16*36];
  __shared__ float whs[3*16*36];
  int tid = threadIdx.x;
  int tx = tid & 15, ty = tid >> 4;
  int jbase = blockIdx.x * 16;
  int bbase = blockIdx.y * 32;

  if (use_caption){
    if (tid < 32) s_tok[tid] = cap[bbase + tid];
  } else {
    int bl = tid >> 3, l8 = tid & 7;
    float best = -INFINITY; int bidx = 0x7fffffff;
    for (int p = l8; p < nvt; p += 8){
      float v = pval[p*BATCH + bbase + bl];
      int   i = pidx[p*BATCH + bbase + bl];
      if (v > best || (v == best && i < bidx)){ best = v; bidx = i; }
    }
    rav[bl*8 + l8] = best; rai[bl*8 + l8] = bidx;
    __syncthreads();
    if (tid < 32){
      float bb = -INFINITY; int bi = 0x7fffffff;
      #pragma unroll
      for (int t=0;t<8;t++){
        float v = rav[tid*8+t]; int i = rai[tid*8+t];
        if (v > bb || (v == bb && i < bi)){ bb = v; bi = i; }
      }
      s_tok[tid] = bi;
      if (blockIdx.x == 0) preds[(bbase+tid)*NT + pred_col] = bi;
    }
  }
  __syncthreads();

  float acc[2][6] = {};
  int lrow = tid >> 3;
  int lc4  = (tid & 7) << 2;
  for (int k0 = 0; k0 < NH; k0 += 32){
    int tokr = s_tok[lrow];
    *(float4*)&xs[lrow*36 + lc4] =
        *(const float4*)(emb + (size_t)tokr*NH + k0 + lc4);
    *(float4*)&hs[lrow*36 + lc4] =
        *(const float4*)(hprev + (size_t)(bbase+lrow)*NH + k0 + lc4);
    #pragma unroll
    for (int qy = tid; qy < 768; qy += 256){
      int g  = qy >> 7;
      int r  = (qy >> 3) & 15;
      int cc = (qy & 7) << 2;
      const float* wsrc = (g < 3) ? wih : whh;
      int gg = (g < 3) ? g : (g - 3);
      float* dst = (g < 3) ? wis : whs;
      *(float4*)&dst[gg*576 + r*36 + cc] =
          *(const float4*)(wsrc + (size_t)(gg*NH + jbase + r)*NH + k0 + cc);
    }
    __syncthreads();
    #pragma unroll
    for (int kk = 0; kk < 32; kk += 4){
      float4 x0 = *(float4*)&xs[ty*36+kk];
      float4 x1 = *(float4*)&xs[(ty+16)*36+kk];
      float4 h0v = *(float4*)&hs[ty*36+kk];
      float4 h1v = *(float4*)&hs[(ty+16)*36+kk];
      #pragma unroll
      for (int g=0; g<3; g++){
        float4 wi4 = *(float4*)&wis[g*576 + tx*36 + kk];
        float4 wh4 = *(float4*)&whs[g*576 + tx*36 + kk];
        acc[0][g]   += x0.x*wi4.x + x0.y*wi4.y + x0.z*wi4.z + x0.w*wi4.w;
        acc[1][g]   += x1.x*wi4.x + x1.y*wi4.y + x1.z*wi4.z + x1.w*wi4.w;
        acc[0][3+g] += h0v.x*wh4.x + h0v.y*wh4.y + h0v.z*wh4.z + h0v.w*wh4.w;
        acc[1][3+g] += h1v.x*wh4.x + h1v.y*wh4.y + h1v.z*wh4.z + h1v.w*wh4.w;
      }
    }
    __syncthreads();
  }
  int j = jbase + tx;
  float bi_r = bih[j], bi_z = bih[j+NH], bi_n = bih[j+2*NH];
  float bh_r = bhh[j], bh_z = bhh[j+NH], bh_n = bhh[j+2*NH];
  #pragma unroll
  for (int i=0;i<2;i++){
    int b = bbase + ty + 16*i;
    float r = 1.f/(1.f + expf(-((acc[i][0]+bi_r) + (acc[i][3]+bh_r))));
    float z = 1.f/(1.f + expf(-((acc[i][1]+bi_z) + (acc[i][4]+bh_z))));
    float n = tanhf((acc[i][2]+bi_n) + r*(acc[i][5]+bh_n));
    float hp = hprev[(size_t)b*NH + j];
    hnew[(size_t)b*NH + j] = (1.f - z)*n + z*hp;
  }
}

__global__ void k_fin(const float* __restrict__ pval, const int* __restrict__ pidx,
                      int* __restrict__ preds, int col, int nvt){
  __shared__ float rav[32*8];
  __shared__ int   rai[32*8];
  int tid = threadIdx.x;
  int bbase = blockIdx.x * 32;
  int bl = tid >> 3, l8 = tid & 7;
  float best = -INFINITY; int bidx = 0x7fffffff;
  for (int p = l8; p < nvt; p += 8){
    float v = pval[p*BATCH + bbase + bl];
    int   i = pidx[p*BATCH + bbase + bl];
    if (v > best || (v == best && i < bidx)){ best = v; bidx = i; }
  }
  rav[bl*8+l8] = best; rai[bl*8+l8] = bidx;
  __syncthreads();
  if (tid < 32){
    float bb = -INFINITY; int bi = 0x7fffffff;
    #pragma unroll
    for (int t=0;t<8;t++){
      float v = rav[tid*8+t]; int i = rai[tid*8+t];
      if (v > bb || (v == bb && i < bi)){ bb = v; bi = i; }
    }
    preds[(bbase+tid)*NT + col] = bi;
  }
}

extern "C" void kernel_launch(void* const* d_in, const int* in_sizes, int n_in,
                              void* d_out, int out_size, void* d_ws, size_t ws_size,
                              hipStream_t stream){
  const int*   cap = (const int*)d_in[0];
  const float* img = (const float*)d_in[1];
  const float* emb = (const float*)d_in[2];
  const float* Wc  = (const float*)d_in[3];
  const float* bc  = (const float*)d_in[4];
  const float* wih = (const float*)d_in[5];
  const float* whh = (const float*)d_in[6];
  const float* bih = (const float*)d_in[7];
  const float* bhh = (const float*)d_in[8];
  const float* Wp  = (const float*)d_in[9];
  const float* bp  = (const float*)d_in[10];
  int* preds = (int*)d_out;

  char* p = (char*)d_ws;
  float* h0b = (float*)p;                   p += (size_t)BATCH*NH*4;
  float* h1b = (float*)p;                   p += (size_t)BATCH*NH*4;
  float* pval = (float*)p;                  p += (size_t)NVT_F32*BATCH*4;
  int*   pidx = (int*)p;                    p += (size_t)NVT_F32*BATCH*4;
  unsigned short* Hhi0 = (unsigned short*)p; p += (size_t)BATCH*NH*2;
  unsigned short* Hlo0 = (unsigned short*)p; p += (size_t)BATCH*NH*2;
  unsigned short* Hhi1 = (unsigned short*)p; p += (size_t)BATCH*NH*2;
  unsigned short* Hlo1 = (unsigned short*)p; p += (size_t)BATCH*NH*2;
  unsigned short* Wt  = (unsigned short*)p;  p += WT_ELEMS*2;            // packed W_pred
  unsigned short* W6hiP = (unsigned short*)p; p += (size_t)3072*NH*2;    // packed [wih;whh]
  unsigned short* W6loP = (unsigned short*)p; p += (size_t)3072*NH*2;
  unsigned short* Wchi = (unsigned short*)p; p += (size_t)NH*NCOND*2;
  unsigned short* Wclo = (unsigned short*)p; p += (size_t)NH*NCOND*2;
  float* rbmax = (float*)p;                  p += (size_t)SPLIT_W_BLOCKS*4 + 60; // pad to 16B
  // zero-init region (one memset): slots | mslots | hsqb | barctr | wn2
  unsigned long long* slots = (unsigned long long*)p; p += (size_t)NT*BATCH*8;
  unsigned long long* mslots = (unsigned long long*)p; p += (size_t)NT*BATCH*8;
  float* hsqb = (float*)p;                   p += (size_t)NT*BATCH*4;
  unsigned* barctr = (unsigned*)p;           p += (size_t)NT*128; // counter+flag per step
  float* wn2 = (float*)p;                    p += 16;
  size_t zero_bytes = (size_t)NT*BATCH*8*2 + (size_t)NT*BATCH*4 + (size_t)NT*128 + 16;
  size_t need = (size_t)(p - (char*)d_ws);

  bool use_mfma = (ws_size >= need);

  k_seed<<<1, 256, 0, stream>>>(cap, preds);
  float* hb[2] = {h0b, h1b};

  if (use_mfma){
    hipMemsetAsync(slots, 0, zero_bytes, stream);
    // zero the padded tail tile of Wt (rows NV..32127) so unwritten rows are 0 not NaN
    hipMemsetAsync(Wt + (size_t)250*65536, 0, (size_t)65536*2, stream);
    k_split_small<<<dim3(SPLIT_S_BLOCKS), 256, 0, stream>>>(wih, whh, Wc,
                                                            W6hiP, W6loP, Wchi, Wclo);
    k_h0_mf<<<dim3(NH/16, BATCH/64), 256, 0, stream>>>(img, Wchi, Wclo, bc,
                                                       h0b, Hhi0, Hlo0);
    unsigned short* Hhs[2] = {Hhi0, Hhi1};
    unsigned short* Hls[2] = {Hlo0, Hlo1};
    k_gru_mf<<<dim3(NH/16, BATCH/32), 256, 0, stream>>>(cap, slots, emb,
        W6hiP, W6loP, Hhs[0], Hls[0], bih, bhh,
        hb[0], hb[1], Hhs[1], Hls[1], preds, hsqb + 1*BATCH, 1, 0);
    k_split_w<<<dim3(SPLIT_W_BLOCKS), 256, 0, stream>>>(Wp, Wt, rbmax);
    k_red_wn<<<1, 256, 0, stream>>>(rbmax, wn2);
    k_predr<<<dim3(NBLK_PRED), 256, 0, stream>>>(Hhs[1], Wt, bp,
        hsqb + 1*BATCH, wn2, hb[1], Wp,
        mslots + 1*BATCH, slots + 1*BATCH, barctr + 1*32);
    for (int s = 2; s <= NT-1; s++){
      int pi = (s-1)&1, ci = s&1;
      k_gru_mf<<<dim3(NH/16, BATCH/32), 256, 0, stream>>>(cap, slots + (size_t)(s-1)*BATCH,
          emb, W6hiP, W6loP, Hhs[pi], Hls[pi], bih, bhh,
          hb[pi], hb[ci], Hhs[ci], Hls[ci], preds, hsqb + (size_t)s*BATCH, 0, s-1);
      k_predr<<<dim3(NBLK_PRED), 256, 0, stream>>>(Hhs[ci], Wt, bp,
          hsqb + (size_t)s*BATCH, wn2, hb[ci], Wp,
          mslots + (size_t)s*BATCH, slots + (size_t)s*BATCH, barctr + (size_t)s*32);
    }
    k_fin_slot<<<1, 256, 0, stream>>>(slots + (size_t)(NT-1)*BATCH, preds);
  } else {
    k_h0_fb<<<dim3(NH/64, BATCH/64), 256, 0, stream>>>(img, Wc, bc, h0b);
    for (int s = 1; s <= NT-1; s++){
      const float* hprev = hb[(s-1)&1];
      float* hnew = hb[s&1];
      k_gru_fb<<<dim3(NH/16, BATCH/32), 256, 0, stream>>>(cap, pval, pidx, emb, wih, whh,
                                                       bih, bhh, hprev, hnew,
                                                       preds, (s==1)?1:0, s-1, NVT_F32);
      k_pred_f32<<<dim3(NVT_F32, BATCH/64), 256, 0, stream>>>(hnew, Wp, bp, pval, pidx);
    }
    k_fin<<<dim3(BATCH/32), 256, 0, stream>>>(pval, pidx, preds, NT-1, NVT_F32);
  }
}